// Round 1
// baseline (311.540 us; speedup 1.0000x reference)
//
#include <hip/hip_runtime.h>
#include <hip/hip_bf16.h>

#define NCELL 32

__global__ __launch_bounds__(256) void cpab_kernel(
    const float* __restrict__ x,
    const float* __restrict__ theta,
    const float* __restrict__ B,
    float* __restrict__ z_out,
    float* __restrict__ lg_out,
    int n)
{
    __shared__ float s_a[NCELL];
    __shared__ float s_b[NCELL];

    const int tid = threadIdx.x;

    // A = B @ theta, B row-major (2N, N+1) = (64, 33).
    // params ordered [a_0, b_0, a_1, b_1, ...]
    if (tid < 2 * NCELL) {
        float acc = 0.f;
        #pragma unroll
        for (int j = 0; j < NCELL + 1; ++j)
            acc += B[tid * (NCELL + 1) + j] * theta[j];
        if (tid & 1) s_b[tid >> 1] = acc;
        else         s_a[tid >> 1] = acc;
    }
    __syncthreads();

    const float Nf     = (float)NCELL;
    const float invN   = 1.0f / (float)NCELL;   // exact (power of 2)
    const float eps    = 1e-10f;
    const float BIG    = 1e10f;
    const float CLIPLO = -1.0f + 1e-6f;

    int i = blockIdx.x * blockDim.x + tid;
    if (i >= n) return;

    float xs = x[i];
    int c = (int)floorf(xs * Nf);
    c = min(max(c, 0), NCELL - 1);
    float t  = 1.0f;
    float lg = 0.0f;

    #pragma unroll 1
    for (int it = 0; it < NCELL + 1; ++it) {
        const float a = s_a[c];
        const float b = s_b[c];
        const float v = a * xs + b;
        const bool  right   = v > 0.0f;
        const float xb      = (right ? (float)(c + 1) : (float)c) * invN;
        const bool  open_b  = right ? (c == NCELL - 1) : (c == 0);
        const bool  small_a = fabsf(a) < eps;
        const bool  small_v = fabsf(v) < eps;
        const float v_safe  = small_v ? eps : v;
        const float a_safe  = small_a ? eps : a;
        const float dxb     = xb - xs;
        const float arg_raw = a * dxb / v_safe;
        const bool  unreach = arg_raw <= CLIPLO;
        const float arg     = fmaxf(arg_raw, CLIPLO);
        float tau = small_a ? (dxb / v_safe) : (log1pf(arg) / a_safe);
        if (open_b || small_v || unreach || (tau < 0.0f)) tau = BIG;
        const bool  hit = (tau <= t);
        const float dt  = hit ? tau : t;
        const float f   = small_a ? dt : (expm1f(a * dt) / a_safe);
        const float x_new = hit ? xb : (xs + v * f);
        lg += a * dt;
        t  -= dt;
        xs  = x_new;
        if (!hit) break;           // t is now 0; remaining scan steps are no-ops
        c += right ? 1 : -1;
        c  = min(max(c, 0), NCELL - 1);
        if (t <= 0.0f) break;      // exhausted budget exactly on a boundary
    }

    z_out[i]  = xs;
    lg_out[i] = lg;
}

extern "C" void kernel_launch(void* const* d_in, const int* in_sizes, int n_in,
                              void* d_out, int out_size, void* d_ws, size_t ws_size,
                              hipStream_t stream)
{
    const float* x     = (const float*)d_in[0];
    const float* theta = (const float*)d_in[1];
    const float* B     = (const float*)d_in[2];
    float* out = (float*)d_out;

    const int n = in_sizes[0];
    float* z_out  = out;
    float* lg_out = out + n;

    const int threads = 256;
    const int blocks  = (n + threads - 1) / threads;
    cpab_kernel<<<blocks, threads, 0, stream>>>(x, theta, B, z_out, lg_out, n);
}

// Round 2
// 57.597 us; speedup vs baseline: 5.4090x; 5.4090x over previous
//
#include <hip/hip_runtime.h>
#include <hip/hip_bf16.h>

#define NCELL 32

// Reference-faithful crossing time for one whole cell (entry knot -> exit knot).
// Returns a value in (0, 2]; 2.0f is the "blocked / takes longer than budget" sentinel
// (budget is always <= 1, so min(tau,2) is search-equivalent to the reference's BIG).
__device__ __forceinline__ float cross_tau(float a, float b, float xs, float xb,
                                           bool need_right, bool open_b)
{
    const float eps    = 1e-10f;
    const float CLIPLO = -1.0f + 1e-6f;
    float v = a * xs + b;
    bool right = v > 0.0f;
    if (right != need_right) return 2.0f;   // cannot be entered in this direction
    bool small_a = fabsf(a) < eps;
    bool small_v = fabsf(v) < eps;
    float v_safe = small_v ? eps : v;
    float a_safe = small_a ? eps : a;
    float dxb = xb - xs;
    float arg_raw = a * dxb / v_safe;
    bool unreach = arg_raw <= CLIPLO;
    float tau = small_a ? (dxb / v_safe)
                        : (log1pf(fmaxf(arg_raw, CLIPLO)) / a_safe);
    if (open_b || small_v || unreach || (tau < 0.0f)) return 2.0f;
    return fminf(tau, 2.0f);
}

__device__ __forceinline__ void solve_point(float xs,
        const float* __restrict__ ta, const float* __restrict__ tb,
        const float* __restrict__ T0, const float* __restrict__ T1,
        const float* __restrict__ G0, const float* __restrict__ G1,
        float& z, float& lg)
{
    const float eps    = 1e-10f;
    const float CLIPLO = -1.0f + 1e-6f;
    const float invN   = 1.0f / (float)NCELL;   // exact (pow2)

    int c = (int)floorf(xs * (float)NCELL);
    c = min(max(c, 0), NCELL - 1);
    float a = ta[c], b = tb[c];
    float v = a * xs + b;
    bool right = v > 0.0f;
    float xb = (right ? (float)(c + 1) : (float)c) * invN;
    bool open_b  = right ? (c == NCELL - 1) : (c == 0);
    bool small_a = fabsf(a) < eps;
    bool small_v = fabsf(v) < eps;
    float v_safe = small_v ? eps : v;
    float a_safe = small_a ? eps : a;
    float dxb = xb - xs;
    float arg_raw = a * dxb / v_safe;
    bool unreach = arg_raw <= CLIPLO;
    float tau0 = small_a ? (dxb / v_safe)
                         : (log1pf(fmaxf(arg_raw, CLIPLO)) / a_safe);
    bool blocked0 = open_b || small_v || unreach || (tau0 < 0.0f);
    bool hit0 = (!blocked0) && (tau0 <= 1.0f);

    float Xf, Df, lg_pre;
    int   Cf;
    if (hit0) {
        int k1   = right ? c + 1 : c;          // knot reached first; in [1,31]
        int idx0 = right ? k1 : NCELL - k1;    // index into direction table
        const float* Tt = right ? T0 : T1;
        const float* Gg = right ? G0 : G1;
        float r    = 1.0f - tau0;
        float base = Tt[idx0];
        int m = idx0;
        #pragma unroll
        for (int bit = 16; bit; bit >>= 1) {
            int cand = m + bit;
            bool ok = (cand <= NCELL) && ((Tt[cand] - base) <= r);
            m = ok ? cand : m;
        }
        float r2 = r - (Tt[m] - base);
        lg_pre = a * tau0 + (Gg[m] - Gg[idx0]);
        int knot = right ? m : NCELL - m;
        Cf = right ? knot : knot - 1;          // final cell, in [0,31] (edges blocked)
        Xf = (float)knot * invN;               // exact knot position
        Df = r2;
    } else {
        lg_pre = 0.0f; Cf = c; Xf = xs; Df = 1.0f;
    }

    // final partial-cell integration (identical formula to reference's no-hit step)
    float A  = ta[Cf], Bc = tb[Cf];
    float V  = A * Xf + Bc;
    bool  sA = fabsf(A) < eps;
    float A_safe = sA ? eps : A;
    float f  = sA ? Df : (expm1f(A * Df) / A_safe);
    z  = Xf + V * f;
    lg = lg_pre + A * Df;
}

__global__ __launch_bounds__(256) void cpab_kernel(
    const float* __restrict__ x,
    const float* __restrict__ theta,
    const float* __restrict__ B,
    float* __restrict__ z_out,
    float* __restrict__ lg_out,
    int n)
{
    __shared__ float ta[NCELL], tb[NCELL];
    __shared__ float taur_s[NCELL], taul_s[NCELL];
    __shared__ float T0[NCELL + 1], T1[NCELL + 1];  // time prefix: right / flipped-left
    __shared__ float G0[NCELL + 1], G1[NCELL + 1];  // a*tau prefix: right / flipped-left

    const int tid = threadIdx.x;
    const float invN = 1.0f / (float)NCELL;

    // A = B @ theta ; B row-major (64, 33), params [a0,b0,a1,b1,...]
    if (tid < 2 * NCELL) {
        float acc = 0.f;
        #pragma unroll
        for (int j = 0; j < NCELL + 1; ++j)
            acc += B[tid * (NCELL + 1) + j] * theta[j];
        if (tid & 1) tb[tid >> 1] = acc;
        else         ta[tid >> 1] = acc;
    }
    __syncthreads();

    if (tid < NCELL) {
        int cc = tid;
        float a = ta[cc], b = tb[cc];
        float xl = (float)cc * invN, xr = (float)(cc + 1) * invN;
        taur_s[cc] = cross_tau(a, b, xl, xr, true,  cc == NCELL - 1);
        taul_s[cc] = cross_tau(a, b, xr, xl, false, cc == 0);
    }
    __syncthreads();

    // inclusive scans (wave 0, lanes 0..31) -> prefix tables
    if (tid < NCELL) {
        int lane = tid;
        float v0 = taur_s[lane];                    // rightward, left-to-right prefix
        float v1 = taul_s[NCELL - 1 - lane];        // leftward, flipped (suffix) prefix
        float g0 = ta[lane] * v0;
        float g1 = ta[NCELL - 1 - lane] * v1;
        #pragma unroll
        for (int off = 1; off < NCELL; off <<= 1) {
            float o0 = __shfl_up(v0, off, 64);
            float o1 = __shfl_up(v1, off, 64);
            float o2 = __shfl_up(g0, off, 64);
            float o3 = __shfl_up(g1, off, 64);
            if (lane >= off) { v0 += o0; v1 += o1; g0 += o2; g1 += o3; }
        }
        T0[lane + 1] = v0; T1[lane + 1] = v1;
        G0[lane + 1] = g0; G1[lane + 1] = g1;
        if (lane == 0) { T0[0] = 0.f; T1[0] = 0.f; G0[0] = 0.f; G1[0] = 0.f; }
    }
    __syncthreads();

    const int gid    = blockIdx.x * blockDim.x + tid;
    const int stride = gridDim.x * blockDim.x;
    const int n4     = n >> 2;

    const float4* __restrict__ x4 = (const float4*)x;
    float4* __restrict__ z4  = (float4*)z_out;
    float4* __restrict__ l4  = (float4*)lg_out;

    for (int j = gid; j < n4; j += stride) {
        float4 xv = x4[j];
        float4 zv, lv;
        solve_point(xv.x, ta, tb, T0, T1, G0, G1, zv.x, lv.x);
        solve_point(xv.y, ta, tb, T0, T1, G0, G1, zv.y, lv.y);
        solve_point(xv.z, ta, tb, T0, T1, G0, G1, zv.z, lv.z);
        solve_point(xv.w, ta, tb, T0, T1, G0, G1, zv.w, lv.w);
        z4[j] = zv;
        l4[j] = lv;
    }
    // tail (n not divisible by 4)
    for (int i = (n4 << 2) + gid; i < n; i += stride) {
        float zz, ll;
        solve_point(x[i], ta, tb, T0, T1, G0, G1, zz, ll);
        z_out[i] = zz;
        lg_out[i] = ll;
    }
}

extern "C" void kernel_launch(void* const* d_in, const int* in_sizes, int n_in,
                              void* d_out, int out_size, void* d_ws, size_t ws_size,
                              hipStream_t stream)
{
    const float* x     = (const float*)d_in[0];
    const float* theta = (const float*)d_in[1];
    const float* B     = (const float*)d_in[2];
    float* out = (float*)d_out;

    const int n = in_sizes[0];
    float* z_out  = out;
    float* lg_out = out + n;

    const int threads = 256;
    const int blocks  = 2048;   // 8 blocks/CU, grid-stride (4 float4 iters/thread)
    cpab_kernel<<<blocks, threads, 0, stream>>>(x, theta, B, z_out, lg_out, n);
}

// Round 3
// 27.633 us; speedup vs baseline: 11.2742x; 2.0843x over previous
//
#include <hip/hip_runtime.h>
#include <hip/hip_bf16.h>

#define NCELL 32
#define KTAB  2048

// ---------- proven round-2 closed form (unchanged numerics) ----------

__device__ __forceinline__ float cross_tau(float a, float b, float xs, float xb,
                                           bool need_right, bool open_b)
{
    const float eps    = 1e-10f;
    const float CLIPLO = -1.0f + 1e-6f;
    float v = a * xs + b;
    bool right = v > 0.0f;
    if (right != need_right) return 2.0f;
    bool small_a = fabsf(a) < eps;
    bool small_v = fabsf(v) < eps;
    float v_safe = small_v ? eps : v;
    float a_safe = small_a ? eps : a;
    float dxb = xb - xs;
    float arg_raw = a * dxb / v_safe;
    bool unreach = arg_raw <= CLIPLO;
    float tau = small_a ? (dxb / v_safe)
                        : (log1pf(fmaxf(arg_raw, CLIPLO)) / a_safe);
    if (open_b || small_v || unreach || (tau < 0.0f)) return 2.0f;
    return fminf(tau, 2.0f);
}

__device__ __forceinline__ void solve_point(float xs,
        const float* __restrict__ ta, const float* __restrict__ tb,
        const float* __restrict__ T0, const float* __restrict__ T1,
        const float* __restrict__ G0, const float* __restrict__ G1,
        float& z, float& lg)
{
    const float eps    = 1e-10f;
    const float CLIPLO = -1.0f + 1e-6f;
    const float invN   = 1.0f / (float)NCELL;

    int c = (int)floorf(xs * (float)NCELL);
    c = min(max(c, 0), NCELL - 1);
    float a = ta[c], b = tb[c];
    float v = a * xs + b;
    bool right = v > 0.0f;
    float xb = (right ? (float)(c + 1) : (float)c) * invN;
    bool open_b  = right ? (c == NCELL - 1) : (c == 0);
    bool small_a = fabsf(a) < eps;
    bool small_v = fabsf(v) < eps;
    float v_safe = small_v ? eps : v;
    float a_safe = small_a ? eps : a;
    float dxb = xb - xs;
    float arg_raw = a * dxb / v_safe;
    bool unreach = arg_raw <= CLIPLO;
    float tau0 = small_a ? (dxb / v_safe)
                         : (log1pf(fmaxf(arg_raw, CLIPLO)) / a_safe);
    bool blocked0 = open_b || small_v || unreach || (tau0 < 0.0f);
    bool hit0 = (!blocked0) && (tau0 <= 1.0f);

    float Xf, Df, lg_pre;
    int   Cf;
    if (hit0) {
        int k1   = right ? c + 1 : c;
        int idx0 = right ? k1 : NCELL - k1;
        const float* Tt = right ? T0 : T1;
        const float* Gg = right ? G0 : G1;
        float r    = 1.0f - tau0;
        float base = Tt[idx0];
        int m = idx0;
        #pragma unroll
        for (int bit = 16; bit; bit >>= 1) {
            int cand = m + bit;
            bool ok = (cand <= NCELL) && ((Tt[cand] - base) <= r);
            m = ok ? cand : m;
        }
        float r2 = r - (Tt[m] - base);
        lg_pre = a * tau0 + (Gg[m] - Gg[idx0]);
        int knot = right ? m : NCELL - m;
        Cf = right ? knot : knot - 1;
        Xf = (float)knot * invN;
        Df = r2;
    } else {
        lg_pre = 0.0f; Cf = c; Xf = xs; Df = 1.0f;
    }

    float A  = ta[Cf], Bc = tb[Cf];
    float V  = A * Xf + Bc;
    bool  sA = fabsf(A) < eps;
    float A_safe = sA ? eps : A;
    float f  = sA ? Df : (expm1f(A * Df) / A_safe);
    z  = Xf + V * f;
    lg = lg_pre + A * Df;
}

// Per-block table setup (A = B@theta, per-cell crossing times, prefix sums).
// Must be called by the full block (contains __syncthreads).
__device__ __forceinline__ void block_setup(
        const float* __restrict__ theta, const float* __restrict__ B,
        float* ta, float* tb, float* taur_s, float* taul_s,
        float* T0, float* T1, float* G0, float* G1)
{
    const int tid = threadIdx.x;
    const float invN = 1.0f / (float)NCELL;

    if (tid < 2 * NCELL) {
        float acc = 0.f;
        #pragma unroll
        for (int j = 0; j < NCELL + 1; ++j)
            acc += B[tid * (NCELL + 1) + j] * theta[j];
        if (tid & 1) tb[tid >> 1] = acc;
        else         ta[tid >> 1] = acc;
    }
    __syncthreads();

    if (tid < NCELL) {
        int cc = tid;
        float a = ta[cc], b = tb[cc];
        float xl = (float)cc * invN, xr = (float)(cc + 1) * invN;
        taur_s[cc] = cross_tau(a, b, xl, xr, true,  cc == NCELL - 1);
        taul_s[cc] = cross_tau(a, b, xr, xl, false, cc == 0);
    }
    __syncthreads();

    if (tid < NCELL) {
        int lane = tid;
        float v0 = taur_s[lane];
        float v1 = taul_s[NCELL - 1 - lane];
        float g0 = ta[lane] * v0;
        float g1 = ta[NCELL - 1 - lane] * v1;
        #pragma unroll
        for (int off = 1; off < NCELL; off <<= 1) {
            float o0 = __shfl_up(v0, off, 64);
            float o1 = __shfl_up(v1, off, 64);
            float o2 = __shfl_up(g0, off, 64);
            float o3 = __shfl_up(g1, off, 64);
            if (lane >= off) { v0 += o0; v1 += o1; g0 += o2; g1 += o3; }
        }
        T0[lane + 1] = v0; T1[lane + 1] = v1;
        G0[lane + 1] = g0; G1[lane + 1] = g1;
        if (lane == 0) { T0[0] = 0.f; T1[0] = 0.f; G0[0] = 0.f; G1[0] = 0.f; }
    }
    __syncthreads();
}

// ---------- kernel 1: build (phi, lg) table at x_j = j/KTAB, j=0..KTAB ----------

__global__ __launch_bounds__(256) void build_table_kernel(
    const float* __restrict__ theta,
    const float* __restrict__ B,
    float2* __restrict__ tab)
{
    __shared__ float ta[NCELL], tb[NCELL];
    __shared__ float taur_s[NCELL], taul_s[NCELL];
    __shared__ float T0[NCELL + 1], T1[NCELL + 1];
    __shared__ float G0[NCELL + 1], G1[NCELL + 1];

    block_setup(theta, B, ta, tb, taur_s, taul_s, T0, T1, G0, G1);

    const float invK = 1.0f / (float)KTAB;
    for (int j = blockIdx.x * blockDim.x + threadIdx.x; j <= KTAB;
         j += gridDim.x * blockDim.x) {
        float xs = (float)j * invK;
        float z, lg;
        solve_point(xs, ta, tb, T0, T1, G0, G1, z, lg);
        tab[j] = make_float2(z, lg);
    }
}

// ---------- kernel 2: memory-bound lerp ----------

__global__ __launch_bounds__(256) void lerp_kernel(
    const float* __restrict__ x,
    const float2* __restrict__ tab,
    float* __restrict__ z_out,
    float* __restrict__ lg_out,
    int n)
{
    __shared__ float2 stab[KTAB + 1];

    const int tid = threadIdx.x;
    for (int j = tid; j <= KTAB; j += blockDim.x)
        stab[j] = tab[j];
    __syncthreads();

    const float Kf = (float)KTAB;
    const int gid    = blockIdx.x * blockDim.x + tid;
    const int stride = gridDim.x * blockDim.x;
    const int n4     = n >> 2;

    const float4* __restrict__ x4 = (const float4*)x;
    float4* __restrict__ z4 = (float4*)z_out;
    float4* __restrict__ l4 = (float4*)lg_out;

    for (int i = gid; i < n4; i += stride) {
        float4 xv = x4[i];
        float4 zv, lv;
        #pragma unroll
        for (int q = 0; q < 4; ++q) {
            float xs = (&xv.x)[q];
            float t  = xs * Kf;
            float jf = floorf(t);
            int   j  = min(max((int)jf, 0), KTAB - 1);
            float f  = t - (float)j;
            float2 p0 = stab[j];
            float2 p1 = stab[j + 1];
            (&zv.x)[q] = fmaf(f, p1.x - p0.x, p0.x);
            (&lv.x)[q] = fmaf(f, p1.y - p0.y, p0.y);
        }
        z4[i] = zv;
        l4[i] = lv;
    }
    for (int i = (n4 << 2) + gid; i < n; i += stride) {
        float xs = x[i];
        float t  = xs * Kf;
        float jf = floorf(t);
        int   j  = min(max((int)jf, 0), KTAB - 1);
        float f  = t - (float)j;
        float2 p0 = stab[j];
        float2 p1 = stab[j + 1];
        z_out[i]  = fmaf(f, p1.x - p0.x, p0.x);
        lg_out[i] = fmaf(f, p1.y - p0.y, p0.y);
    }
}

// ---------- fallback: proven round-2 kernel (if ws too small) ----------

__global__ __launch_bounds__(256) void cpab_fallback_kernel(
    const float* __restrict__ x,
    const float* __restrict__ theta,
    const float* __restrict__ B,
    float* __restrict__ z_out,
    float* __restrict__ lg_out,
    int n)
{
    __shared__ float ta[NCELL], tb[NCELL];
    __shared__ float taur_s[NCELL], taul_s[NCELL];
    __shared__ float T0[NCELL + 1], T1[NCELL + 1];
    __shared__ float G0[NCELL + 1], G1[NCELL + 1];

    block_setup(theta, B, ta, tb, taur_s, taul_s, T0, T1, G0, G1);

    const int gid    = blockIdx.x * blockDim.x + threadIdx.x;
    const int stride = gridDim.x * blockDim.x;
    const int n4     = n >> 2;

    const float4* __restrict__ x4 = (const float4*)x;
    float4* __restrict__ z4 = (float4*)z_out;
    float4* __restrict__ l4 = (float4*)lg_out;

    for (int j = gid; j < n4; j += stride) {
        float4 xv = x4[j];
        float4 zv, lv;
        solve_point(xv.x, ta, tb, T0, T1, G0, G1, zv.x, lv.x);
        solve_point(xv.y, ta, tb, T0, T1, G0, G1, zv.y, lv.y);
        solve_point(xv.z, ta, tb, T0, T1, G0, G1, zv.z, lv.z);
        solve_point(xv.w, ta, tb, T0, T1, G0, G1, zv.w, lv.w);
        z4[j] = zv;
        l4[j] = lv;
    }
    for (int i = (n4 << 2) + gid; i < n; i += stride) {
        float zz, ll;
        solve_point(x[i], ta, tb, T0, T1, G0, G1, zz, ll);
        z_out[i] = zz;
        lg_out[i] = ll;
    }
}

extern "C" void kernel_launch(void* const* d_in, const int* in_sizes, int n_in,
                              void* d_out, int out_size, void* d_ws, size_t ws_size,
                              hipStream_t stream)
{
    const float* x     = (const float*)d_in[0];
    const float* theta = (const float*)d_in[1];
    const float* B     = (const float*)d_in[2];
    float* out = (float*)d_out;

    const int n = in_sizes[0];
    float* z_out  = out;
    float* lg_out = out + n;

    const size_t tab_bytes = (size_t)(KTAB + 1) * sizeof(float2);

    if (ws_size >= tab_bytes) {
        float2* tab = (float2*)d_ws;
        build_table_kernel<<<(KTAB + 256) / 256, 256, 0, stream>>>(theta, B, tab);
        lerp_kernel<<<1024, 256, 0, stream>>>(x, tab, z_out, lg_out, n);
    } else {
        cpab_fallback_kernel<<<2048, 256, 0, stream>>>(x, theta, B, z_out, lg_out, n);
    }
}